// Round 3
// baseline (600.081 us; speedup 1.0000x reference)
//
#include <hip/hip_runtime.h>
#include <math.h>

#define BB 2
#define LL 5
#define CC 256
#define HH 100
#define WW 252
#define HW (HH*WW)
#define CHW (CC*HW)
#define THRE_F 0.01f

// channel-chunking: 4 chunks x 64 channels; each of 4 wave-groups does 16
#define NCC 4
#define CI_PER_CG 16

typedef float v2f __attribute__((ext_vector_type(2)));
typedef float v4f __attribute__((ext_vector_type(4)));

__device__ __forceinline__ v2f ld2v(const float* p) {
    v2f v; __builtin_memcpy(&v, p, 8); return v;
}
__device__ __forceinline__ v4f ld4v(const float* p) {
    v4f v; __builtin_memcpy(&v, p, 16); return v;
}
__device__ __forceinline__ void st2v(float* p, v2f v) {
    __builtin_memcpy(p, &v, 8);
}
// non-temporal 8B store: out's writes shouldn't evict x lines still needed.
__device__ __forceinline__ void st2v_nt(float* p, v2f v) {
    __builtin_nontemporal_store(v, (v2f*)p);
}
__device__ __forceinline__ float dot8(const float* c, v4f A, v4f B) {
    return c[0]*A.x + c[1]*A.y + c[2]*A.z + c[3]*A.w
         + c[4]*B.x + c[5]*B.y + c[6]*B.z + c[7]*B.w;
}

// XCD-aware bijective swizzle: dispatch i lands on XCD i%8 (m09); give each
// XCD a contiguous chunk of logical block ids so h and h+1 share an L2.
__device__ __forceinline__ int xcd_swizzle(int blk, int nblk) {
    int q = nblk >> 3;              // nblk % 8 == 0 for our grids
    return (blk & 7) * q + (blk >> 3);
}

// 5x5 gaussian, sigma=1 (float literals, no runtime exp)
__device__ const float GW[5][5] = {
    {0.002915024f, 0.013064233f, 0.021539279f, 0.013064233f, 0.002915024f},
    {0.013064233f, 0.058549832f, 0.096532353f, 0.058549832f, 0.013064233f},
    {0.021539279f, 0.096532353f, 0.159154943f, 0.096532353f, 0.021539279f},
    {0.013064233f, 0.058549832f, 0.096532353f, 0.058549832f, 0.013064233f},
    {0.002915024f, 0.013064233f, 0.021539279f, 0.013064233f, 0.002915024f},
};

// ---------------------------------------------------------------------------
// Kernel 1: confidence mask for odd agents. m in [0,4): n in {1,3,6,8}
// ---------------------------------------------------------------------------
__global__ void mask_kernel(const float* __restrict__ psm, float* __restrict__ mask)
{
    int idx = blockIdx.x * blockDim.x + threadIdx.x;
    if (idx >= 4 * HW) return;
    int m = idx / HW;
    int p = idx - m * HW;
    int h = p / WW;
    int w = p - h * WW;
    int n = (m >> 1) * LL + ((m & 1) * 2 + 1);
    const float* base0 = psm + (size_t)n * 2 * HW;
    const float* base1 = base0 + HW;

    float acc = 0.0f;
#pragma unroll
    for (int i = 0; i < 5; ++i) {
        int yy = h + i - 2;
        if (yy < 0 || yy >= HH) continue;
#pragma unroll
        for (int j = 0; j < 5; ++j) {
            int xx = w + j - 2;
            if (xx < 0 || xx >= WW) continue;
            float v = fmaxf(base0[yy * WW + xx], base1[yy * WW + xx]);
            acc += GW[i][j] / (1.0f + __expf(-v));
        }
    }
    mask[idx] = (acc > THRE_F) ? 1.0f : 0.0f;
}

// ---------------------------------------------------------------------------
// Transform decode (theta row pair, pre-scaled per reference)
// ---------------------------------------------------------------------------
struct XF { float t00, t01, t02, t10, t11, t12; };

__device__ __forceinline__ XF load_xf(const float* __restrict__ pt, int b, int l) {
    const float* M = pt + (size_t)(b * LL * LL + l) * 16;  // pairwise[b,0,l]
    XF X;
    X.t00 = M[0];
    X.t01 = M[1] * (100.0f / 252.0f);
    X.t02 = M[3] / 403.2f * 2.0f;
    X.t10 = M[4] * (252.0f / 100.0f);
    X.t11 = M[5];
    X.t12 = M[7] / 160.0f * 2.0f;
    return X;
}
__device__ __forceinline__ bool is_trans(const XF& X) {
    return X.t00 == 1.0f && X.t01 == 0.0f && X.t10 == 0.0f && X.t11 == 1.0f;
}

// ---------------------------------------------------------------------------
// Translation fast-path tap setup for one agent l: lane owns pixels px0,px0+1.
// One 4-float window at even col covers all x-taps of both pixels; borders,
// validity, conv-mask and tile-activity folded into cf[16]:
//   cf[px*8 + row*4 + e]  multiplies window element e of row (y0,y1).
// ---------------------------------------------------------------------------
__device__ __forceinline__ void setup_trans(
    int l, int b, int h, int px0, float act, const XF& X,
    const float* __restrict__ maskw, int cstart,
    float cf[16], int o2[2])
{
    float tx = X.t02 * (WW * 0.5f);
    float ty = X.t12 * (HH * 0.5f);
    int ix = (int)floorf(tx);
    int iy = (int)floorf(ty);
    float wx1 = tx - (float)ix, wx0 = 1.0f - wx1;
    float wy1 = ty - (float)iy, wy0 = 1.0f - wy1;
    int y0 = h + iy, y1 = y0 + 1;
    int cy0 = min(max(y0, 0), HH - 1), cy1 = min(max(y1, 0), HH - 1);
    float vy0 = (y0 >= 0 && y0 < HH) ? 1.0f : 0.0f;
    float vy1 = (y1 >= 0 && y1 < HH) ? 1.0f : 0.0f;

    int craw = px0 + ix;
    int col = craw & ~1;
    col = min(max(col, 0), WW - 4);
    int d = craw - col;          // <= 3 (may be negative at left border)

    const float* mb = nullptr;
    if (l & 1) mb = maskw + (size_t)(b * 2 + (l >> 1)) * HW;

#pragma unroll
    for (int k = 0; k < 16; ++k) cf[k] = 0.0f;
#pragma unroll
    for (int px = 0; px < 2; ++px) {
#pragma unroll
        for (int r = 0; r < 2; ++r) {
#pragma unroll
            for (int t = 0; t < 2; ++t) {
                int xt = craw + px + t;
                float vx  = (xt >= 0 && xt < WW) ? 1.0f : 0.0f;
                float wcol = t ? wx1 : wx0;
                float wrow = r ? wy1 : wy0;
                float vyw  = r ? vy1 : vy0;
                float m = 1.0f;
                if (mb) {
                    int cx = min(max(xt, 0), WW - 1);
                    int cy = r ? cy1 : cy0;
                    m = mb[cy * WW + cx];
                }
                float wgt = wcol * wrow * vyw * vx * m * act;
                int e = d + px + t;
#pragma unroll
                for (int k = 0; k < 4; ++k)
                    if (e == k) cf[px * 8 + r * 4 + k] += wgt;
            }
        }
    }
    int nbase = (b * LL + l) * CHW + cstart * HW;
    o2[0] = nbase + cy0 * WW + col;
    o2[1] = nbase + cy1 * WW + col;
}

// ---------------------------------------------------------------------------
// General-affine tap setup (fallback; not exercised by translation inputs).
// Per pixel px: float2 loads at rows y0/y1, coefs gc[px*4 + {a0,b0,a1,b1}].
// ---------------------------------------------------------------------------
__device__ __forceinline__ void setup_gen(
    int l, int b, int h, int px0, float act, const XF& X,
    const float* __restrict__ maskw, int cstart,
    float gc[8], int o4[4])
{
    const float* mb = nullptr;
    if (l & 1) mb = maskw + (size_t)(b * 2 + (l >> 1)) * HW;
    float ysn = (h + 0.5f) * (2.0f / HH) - 1.0f;
    int nbase = (b * LL + l) * CHW + cstart * HW;

#pragma unroll
    for (int px = 0; px < 2; ++px) {
        float xsn = (px0 + px + 0.5f) * (2.0f / WW) - 1.0f;
        float gx = X.t00 * xsn + X.t01 * ysn + X.t02;
        float gy = X.t10 * xsn + X.t11 * ysn + X.t12;
        float fx = ((gx + 1.0f) * WW - 1.0f) * 0.5f;
        float fy = ((gy + 1.0f) * HH - 1.0f) * 0.5f;
        float fx0 = floorf(fx), fy0 = floorf(fy);
        float wx1 = fx - fx0, wy1 = fy - fy0;
        float wx0 = 1.0f - wx1, wy0 = 1.0f - wy1;
        int x0 = (int)fx0, y0 = (int)fy0;
        int x1 = x0 + 1, y1 = y0 + 1;
        int cx0 = min(max(x0, 0), WW - 1), cx1 = min(max(x1, 0), WW - 1);
        int cy0 = min(max(y0, 0), HH - 1), cy1 = min(max(y1, 0), HH - 1);
        float vx0 = (x0 >= 0 && x0 < WW) ? 1.0f : 0.0f;
        float vx1 = (x1 >= 0 && x1 < WW) ? 1.0f : 0.0f;
        float vy0 = (y0 >= 0 && y0 < HH) ? 1.0f : 0.0f;
        float vy1 = (y1 >= 0 && y1 < HH) ? 1.0f : 0.0f;
        float m00 = 1, m01 = 1, m10 = 1, m11 = 1;
        if (mb) {
            m00 = mb[cy0 * WW + cx0]; m01 = mb[cy0 * WW + cx1];
            m10 = mb[cy1 * WW + cx0]; m11 = mb[cy1 * WW + cx1];
        }
        float w00 = wx0 * wy0 * vx0 * vy0 * m00 * act;
        float w01 = wx1 * wy0 * vx1 * vy0 * m01 * act;
        float w10 = wx0 * wy1 * vx0 * vy1 * m10 * act;
        float w11 = wx1 * wy1 * vx1 * vy1 * m11 * act;
        int bx = min(max(x0, 0), WW - 2);
        int dd = x0 - bx;
        gc[px * 4 + 0] = (dd == 0 ? w00 : 0.f) + (dd == -1 ? w01 : 0.f);
        gc[px * 4 + 1] = (dd == 0 ? w01 : 0.f) + (dd ==  1 ? w00 : 0.f);
        gc[px * 4 + 2] = (dd == 0 ? w10 : 0.f) + (dd == -1 ? w11 : 0.f);
        gc[px * 4 + 3] = (dd == 0 ? w11 : 0.f) + (dd ==  1 ? w10 : 0.f);
        o4[px * 2 + 0] = nbase + cy0 * WW + bx;
        o4[px * 2 + 1] = nbase + cy1 * WW + bx;
    }
}

// ---------------------------------------------------------------------------
// Kernel 2: partial attention scores.
// Block = (b, h, wtile of 128 px, cchunk of 64 c). 256 thr = 4 cg x 64 lanes,
// each lane owns 2 adjacent pixels; each cg reduces 16 channels.
// Fast path is software-pipelined: window loads for ci+1 issue while ci's
// dot products consume the held registers (depth-1 prefetch).
// ---------------------------------------------------------------------------
__global__ __launch_bounds__(256, 4) void score_kernel(
    const float* __restrict__ x, const float* __restrict__ pt,
    const float* __restrict__ maskw, float* __restrict__ scoresP)
{
    int blk = xcd_swizzle(blockIdx.x, gridDim.x);
    int cc = blk & (NCC - 1);
    int wt = (blk >> 2) & 1;
    int t  = blk >> 3;
    int h  = t % HH;
    int b  = t / HH;

    int tid = threadIdx.x;
    int lane = tid & 63;
    int cg   = tid >> 6;
    int px0  = wt * 128 + 2 * lane;
    float act = (px0 < WW) ? 1.0f : 0.0f;
    v2f act2 = {act, act};
    int cstart = cc * (CC / NCC) + cg * CI_PER_CG;

    XF X[LL];
#pragma unroll
    for (int l = 0; l < LL; ++l) X[l] = load_xf(pt, b, l);
    bool ident0 = is_trans(X[0]) && X[0].t02 == 0.0f && X[0].t12 == 0.0f;
    bool ftrans = ident0 && is_trans(X[1]) && is_trans(X[2])
                         && is_trans(X[3]) && is_trans(X[4]);

    v2f s[LL];
#pragma unroll
    for (int l = 0; l < LL; ++l) s[l] = (v2f){0.f, 0.f};

    if (ftrans) {
        int f0off = b * LL * CHW + cstart * HW + h * WW + min(px0, WW - 2);
        float cf[4][16];
        int o[8];
#pragma unroll
        for (int l = 1; l < LL; ++l)
            setup_trans(l, b, h, px0, act, X[l], maskw, cstart, cf[l - 1], &o[(l - 1) * 2]);

        // prologue: load ci=0 operands
        v2f f0v = ld2v(x + f0off);  f0off += HW;
        v4f Fa[4], Fb[4];
#pragma unroll
        for (int l = 0; l < 4; ++l) {
            Fa[l] = ld4v(x + o[2 * l]);     o[2 * l]     += HW;
            Fb[l] = ld4v(x + o[2 * l + 1]); o[2 * l + 1] += HW;
        }

        for (int ci = 0; ci < CI_PER_CG; ++ci) {
            bool more = (ci + 1 < CI_PER_CG);
            v2f f0 = f0v * act2;
            if (more) { f0v = ld2v(x + f0off); f0off += HW; }
            s[0] += f0 * f0;
#pragma unroll
            for (int l = 0; l < 4; ++l) {
                v4f A = Fa[l], B = Fb[l];
                if (more) {
                    Fa[l] = ld4v(x + o[2 * l]);     o[2 * l]     += HW;
                    Fb[l] = ld4v(x + o[2 * l + 1]); o[2 * l + 1] += HW;
                }
                v2f fl;
                fl.x = dot8(&cf[l][0], A, B);
                fl.y = dot8(&cf[l][8], A, B);
                s[l + 1] += f0 * fl;
            }
        }
    } else {
        float gc[LL][8];
        int go[LL][4];
#pragma unroll
        for (int l = 0; l < LL; ++l)
            setup_gen(l, b, h, px0, act, X[l], maskw, cstart, gc[l], go[l]);

        for (int ci = 0; ci < CI_PER_CG; ++ci) {
            v2f fv[LL];
#pragma unroll
            for (int l = 0; l < LL; ++l) {
                v2f R00 = ld2v(x + go[l][0]);
                v2f R01 = ld2v(x + go[l][1]);
                v2f R10 = ld2v(x + go[l][2]);
                v2f R11 = ld2v(x + go[l][3]);
#pragma unroll
                for (int k = 0; k < 4; ++k) go[l][k] += HW;
                fv[l].x = gc[l][0]*R00.x + gc[l][1]*R00.y + gc[l][2]*R01.x + gc[l][3]*R01.y;
                fv[l].y = gc[l][4]*R10.x + gc[l][5]*R10.y + gc[l][6]*R11.x + gc[l][7]*R11.y;
            }
#pragma unroll
            for (int l = 0; l < LL; ++l) s[l] += fv[0] * fv[l];
        }
    }

    __shared__ v2f sred[4][LL][64];
#pragma unroll
    for (int l = 0; l < LL; ++l) sred[cg][l][lane] = s[l];
    __syncthreads();

    if (tid < 64 && px0 < WW) {
        int p = h * WW + px0;
#pragma unroll
        for (int l = 0; l < LL; ++l) {
            v2f v = (sred[0][l][lane] + sred[1][l][lane]
                   + sred[2][l][lane] + sred[3][l][lane]) * 0.0625f;  // /sqrt(256)
            st2v(&scoresP[((cc * BB + b) * LL + l) * HW + p], v);
        }
    }
}

// ---------------------------------------------------------------------------
// Kernel 3: softmax over L (per thread from score partials) + weighted gather.
// Attention folded into tap coefficients. ci walks DESCENDING (tail of
// score's stream is the freshest cached data); nt stores. Same depth-1
// software pipeline as score_kernel.
// ---------------------------------------------------------------------------
__global__ __launch_bounds__(256, 4) void out_kernel(
    const float* __restrict__ x, const float* __restrict__ pt,
    const float* __restrict__ maskw, const float* __restrict__ scoresP,
    float* __restrict__ out)
{
    int blk = xcd_swizzle(blockIdx.x, gridDim.x);
    int cc = blk & (NCC - 1);
    int wt = (blk >> 2) & 1;
    int t  = blk >> 3;
    int h  = t % HH;
    int b  = t / HH;

    int tid = threadIdx.x;
    int lane = tid & 63;
    int cg   = tid >> 6;
    int px0  = wt * 128 + 2 * lane;
    float act = (px0 < WW) ? 1.0f : 0.0f;
    v2f act2 = {act, act};
    int cstart = cc * (CC / NCC) + cg * CI_PER_CG;

    // softmax over agents, per pixel pair (sum the 4 channel-chunk partials)
    v2f a[LL];
    {
        int p = min(h * WW + px0, HW - 2);
        v2f mx = {-1e30f, -1e30f};
#pragma unroll
        for (int l = 0; l < LL; ++l) {
            v2f sc = {0.f, 0.f};
#pragma unroll
            for (int q = 0; q < NCC; ++q)
                sc += ld2v(scoresP + ((q * BB + b) * LL + l) * HW + p);
            a[l] = sc;
            mx.x = fmaxf(mx.x, sc.x);
            mx.y = fmaxf(mx.y, sc.y);
        }
        v2f denom = {0.f, 0.f};
#pragma unroll
        for (int l = 0; l < LL; ++l) {
            a[l].x = __expf(a[l].x - mx.x);
            a[l].y = __expf(a[l].y - mx.y);
            denom += a[l];
        }
        v2f inv = {1.0f / denom.x, 1.0f / denom.y};
#pragma unroll
        for (int l = 0; l < LL; ++l) a[l] *= inv;
    }

    XF X[LL];
#pragma unroll
    for (int l = 0; l < LL; ++l) X[l] = load_xf(pt, b, l);
    bool ident0 = is_trans(X[0]) && X[0].t02 == 0.0f && X[0].t12 == 0.0f;
    bool ftrans = ident0 && is_trans(X[1]) && is_trans(X[2])
                         && is_trans(X[3]) && is_trans(X[4]);

    // start at the LAST channel of this cg's strip and walk down
    int obase = b * CHW + cstart * HW + h * WW + px0 + (CI_PER_CG - 1) * HW;
    bool doStore = (px0 < WW);

    if (ftrans) {
        int f0off = b * LL * CHW + cstart * HW + h * WW + min(px0, WW - 2)
                  + (CI_PER_CG - 1) * HW;
        float cf[4][16];
        int o[8];
#pragma unroll
        for (int l = 1; l < LL; ++l) {
            setup_trans(l, b, h, px0, act, X[l], maskw, cstart, cf[l - 1], &o[(l - 1) * 2]);
            o[(l - 1) * 2 + 0] += (CI_PER_CG - 1) * HW;
            o[(l - 1) * 2 + 1] += (CI_PER_CG - 1) * HW;
#pragma unroll
            for (int k = 0; k < 8; ++k) {           // fold attn per pixel
                cf[l - 1][k]     *= a[l].x;
                cf[l - 1][k + 8] *= a[l].y;
            }
        }
        v2f af0 = a[0] * act2;

        // prologue: load first (topmost) channel's operands
        v2f f0v = ld2v(x + f0off);  f0off -= HW;
        v4f Fa[4], Fb[4];
#pragma unroll
        for (int l = 0; l < 4; ++l) {
            Fa[l] = ld4v(x + o[2 * l]);     o[2 * l]     -= HW;
            Fb[l] = ld4v(x + o[2 * l + 1]); o[2 * l + 1] -= HW;
        }

        for (int ci = 0; ci < CI_PER_CG; ++ci) {
            bool more = (ci + 1 < CI_PER_CG);
            v2f f0 = f0v;
            if (more) { f0v = ld2v(x + f0off); f0off -= HW; }
            v2f ctx = af0 * f0;
#pragma unroll
            for (int l = 0; l < 4; ++l) {
                v4f A = Fa[l], B = Fb[l];
                if (more) {
                    Fa[l] = ld4v(x + o[2 * l]);     o[2 * l]     -= HW;
                    Fb[l] = ld4v(x + o[2 * l + 1]); o[2 * l + 1] -= HW;
                }
                ctx.x += dot8(&cf[l][0], A, B);
                ctx.y += dot8(&cf[l][8], A, B);
            }
            if (doStore) st2v_nt(&out[obase], ctx);
            obase -= HW;
        }
    } else {
        float gc[LL][8];
        int go[LL][4];
#pragma unroll
        for (int l = 0; l < LL; ++l) {
            setup_gen(l, b, h, px0, act, X[l], maskw, cstart, gc[l], go[l]);
#pragma unroll
            for (int k = 0; k < 4; ++k) {
                go[l][k] += (CI_PER_CG - 1) * HW;
            }
#pragma unroll
            for (int k = 0; k < 4; ++k) {
                gc[l][k]     *= a[l].x;
                gc[l][k + 4] *= a[l].y;
            }
        }
        for (int ci = 0; ci < CI_PER_CG; ++ci) {
            v2f ctx = {0.f, 0.f};
#pragma unroll
            for (int l = 0; l < LL; ++l) {
                v2f R00 = ld2v(x + go[l][0]);
                v2f R01 = ld2v(x + go[l][1]);
                v2f R10 = ld2v(x + go[l][2]);
                v2f R11 = ld2v(x + go[l][3]);
#pragma unroll
                for (int k = 0; k < 4; ++k) go[l][k] -= HW;
                ctx.x += gc[l][0]*R00.x + gc[l][1]*R00.y + gc[l][2]*R01.x + gc[l][3]*R01.y;
                ctx.y += gc[l][4]*R10.x + gc[l][5]*R10.y + gc[l][6]*R11.x + gc[l][7]*R11.y;
            }
            if (doStore) st2v_nt(&out[obase], ctx);
            obase -= HW;
        }
    }
}

extern "C" void kernel_launch(void* const* d_in, const int* in_sizes, int n_in,
                              void* d_out, int out_size, void* d_ws, size_t ws_size,
                              hipStream_t stream)
{
    const float* x   = (const float*)d_in[0];   // (10, 256, 100, 252)
    const float* psm = (const float*)d_in[1];   // (10, 2, 100, 252)
    const float* pt  = (const float*)d_in[2];   // (2, 5, 5, 4, 4)
    float* out = (float*)d_out;                 // (2, 256, 100, 252)

    float* maskw  = (float*)d_ws;               // 4*HW floats
    float* scores = maskw + 4 * HW;             // NCC*B*L*HW floats

    mask_kernel<<<(4 * HW + 255) / 256, 256, 0, stream>>>(psm, maskw);
    score_kernel<<<BB * HH * 2 * NCC, 256, 0, stream>>>(x, pt, maskw, scores);
    out_kernel<<<BB * HH * 2 * NCC, 256, 0, stream>>>(x, pt, maskw, scores, out);
}

// Round 4
// 481.544 us; speedup vs baseline: 1.2462x; 1.2462x over previous
//
#include <hip/hip_runtime.h>
#include <math.h>

#define BB 2
#define LL 5
#define CC 256
#define HH 100
#define WW 252
#define HW (HH*WW)
#define CHW (CC*HW)
#define THRE_F 0.01f

// channel-chunking: 4 chunks x 64 channels; each of 4 wave-groups does 16
#define NCC 4
#define CI_PER_CG 16

typedef float v2f __attribute__((ext_vector_type(2)));
typedef float v4f __attribute__((ext_vector_type(4)));

__device__ __forceinline__ v2f ld2v(const float* p) {
    v2f v; __builtin_memcpy(&v, p, 8); return v;
}
__device__ __forceinline__ v4f ld4v(const float* p) {
    v4f v; __builtin_memcpy(&v, p, 16); return v;
}
__device__ __forceinline__ void st2v(float* p, v2f v) {
    __builtin_memcpy(p, &v, 8);
}
__device__ __forceinline__ float dot8(const float* c, v4f A, v4f B) {
    return c[0]*A.x + c[1]*A.y + c[2]*A.z + c[3]*A.w
         + c[4]*B.x + c[5]*B.y + c[6]*B.z + c[7]*B.w;
}

// XCD-aware bijective swizzle: dispatch i lands on XCD i%8 (m09); give each
// XCD a contiguous chunk of logical block ids so h and h+1 share an L2.
__device__ __forceinline__ int xcd_swizzle(int blk, int nblk) {
    int q = nblk >> 3;              // nblk % 8 == 0 for our grids
    return (blk & 7) * q + (blk >> 3);
}

// 5x5 gaussian, sigma=1 (float literals, no runtime exp)
__device__ const float GW[5][5] = {
    {0.002915024f, 0.013064233f, 0.021539279f, 0.013064233f, 0.002915024f},
    {0.013064233f, 0.058549832f, 0.096532353f, 0.058549832f, 0.013064233f},
    {0.021539279f, 0.096532353f, 0.159154943f, 0.096532353f, 0.021539279f},
    {0.013064233f, 0.058549832f, 0.096532353f, 0.058549832f, 0.013064233f},
    {0.002915024f, 0.013064233f, 0.021539279f, 0.013064233f, 0.002915024f},
};

// ---------------------------------------------------------------------------
// Kernel 1: confidence mask for odd agents. m in [0,4): n in {1,3,6,8}
// ---------------------------------------------------------------------------
__global__ void mask_kernel(const float* __restrict__ psm, float* __restrict__ mask)
{
    int idx = blockIdx.x * blockDim.x + threadIdx.x;
    if (idx >= 4 * HW) return;
    int m = idx / HW;
    int p = idx - m * HW;
    int h = p / WW;
    int w = p - h * WW;
    int n = (m >> 1) * LL + ((m & 1) * 2 + 1);
    const float* base0 = psm + (size_t)n * 2 * HW;
    const float* base1 = base0 + HW;

    float acc = 0.0f;
#pragma unroll
    for (int i = 0; i < 5; ++i) {
        int yy = h + i - 2;
        if (yy < 0 || yy >= HH) continue;
#pragma unroll
        for (int j = 0; j < 5; ++j) {
            int xx = w + j - 2;
            if (xx < 0 || xx >= WW) continue;
            float v = fmaxf(base0[yy * WW + xx], base1[yy * WW + xx]);
            acc += GW[i][j] / (1.0f + __expf(-v));
        }
    }
    mask[idx] = (acc > THRE_F) ? 1.0f : 0.0f;
}

// ---------------------------------------------------------------------------
// Transform decode (theta row pair, pre-scaled per reference)
// ---------------------------------------------------------------------------
struct XF { float t00, t01, t02, t10, t11, t12; };

__device__ __forceinline__ XF load_xf(const float* __restrict__ pt, int b, int l) {
    const float* M = pt + (size_t)(b * LL * LL + l) * 16;  // pairwise[b,0,l]
    XF X;
    X.t00 = M[0];
    X.t01 = M[1] * (100.0f / 252.0f);
    X.t02 = M[3] / 403.2f * 2.0f;
    X.t10 = M[4] * (252.0f / 100.0f);
    X.t11 = M[5];
    X.t12 = M[7] / 160.0f * 2.0f;
    return X;
}
__device__ __forceinline__ bool is_trans(const XF& X) {
    return X.t00 == 1.0f && X.t01 == 0.0f && X.t10 == 0.0f && X.t11 == 1.0f;
}

// ---------------------------------------------------------------------------
// Translation fast-path tap setup for one agent l: lane owns pixels px0,px0+1.
// One 4-float window at even col covers all x-taps of both pixels; borders,
// validity, conv-mask and tile-activity folded into cf[16]:
//   cf[px*8 + row*4 + e]  multiplies window element e of row (y0,y1).
// ---------------------------------------------------------------------------
__device__ __forceinline__ void setup_trans(
    int l, int b, int h, int px0, float act, const XF& X,
    const float* __restrict__ maskw, int cstart,
    float cf[16], int o2[2])
{
    float tx = X.t02 * (WW * 0.5f);
    float ty = X.t12 * (HH * 0.5f);
    int ix = (int)floorf(tx);
    int iy = (int)floorf(ty);
    float wx1 = tx - (float)ix, wx0 = 1.0f - wx1;
    float wy1 = ty - (float)iy, wy0 = 1.0f - wy1;
    int y0 = h + iy, y1 = y0 + 1;
    int cy0 = min(max(y0, 0), HH - 1), cy1 = min(max(y1, 0), HH - 1);
    float vy0 = (y0 >= 0 && y0 < HH) ? 1.0f : 0.0f;
    float vy1 = (y1 >= 0 && y1 < HH) ? 1.0f : 0.0f;

    int craw = px0 + ix;
    int col = craw & ~1;
    col = min(max(col, 0), WW - 4);
    int d = craw - col;          // <= 3 (may be negative at left border)

    const float* mb = nullptr;
    if (l & 1) mb = maskw + (size_t)(b * 2 + (l >> 1)) * HW;

#pragma unroll
    for (int k = 0; k < 16; ++k) cf[k] = 0.0f;
#pragma unroll
    for (int px = 0; px < 2; ++px) {
#pragma unroll
        for (int r = 0; r < 2; ++r) {
#pragma unroll
            for (int t = 0; t < 2; ++t) {
                int xt = craw + px + t;
                float vx  = (xt >= 0 && xt < WW) ? 1.0f : 0.0f;
                float wcol = t ? wx1 : wx0;
                float wrow = r ? wy1 : wy0;
                float vyw  = r ? vy1 : vy0;
                float m = 1.0f;
                if (mb) {
                    int cx = min(max(xt, 0), WW - 1);
                    int cy = r ? cy1 : cy0;
                    m = mb[cy * WW + cx];
                }
                float wgt = wcol * wrow * vyw * vx * m * act;
                int e = d + px + t;
#pragma unroll
                for (int k = 0; k < 4; ++k)
                    if (e == k) cf[px * 8 + r * 4 + k] += wgt;
            }
        }
    }
    int nbase = (b * LL + l) * CHW + cstart * HW;
    o2[0] = nbase + cy0 * WW + col;
    o2[1] = nbase + cy1 * WW + col;
}

// ---------------------------------------------------------------------------
// General-affine tap setup (fallback; not exercised by translation inputs).
// Per pixel px: float2 loads at rows y0/y1, coefs gc[px*4 + {a0,b0,a1,b1}].
// ---------------------------------------------------------------------------
__device__ __forceinline__ void setup_gen(
    int l, int b, int h, int px0, float act, const XF& X,
    const float* __restrict__ maskw, int cstart,
    float gc[8], int o4[4])
{
    const float* mb = nullptr;
    if (l & 1) mb = maskw + (size_t)(b * 2 + (l >> 1)) * HW;
    float ysn = (h + 0.5f) * (2.0f / HH) - 1.0f;
    int nbase = (b * LL + l) * CHW + cstart * HW;

#pragma unroll
    for (int px = 0; px < 2; ++px) {
        float xsn = (px0 + px + 0.5f) * (2.0f / WW) - 1.0f;
        float gx = X.t00 * xsn + X.t01 * ysn + X.t02;
        float gy = X.t10 * xsn + X.t11 * ysn + X.t12;
        float fx = ((gx + 1.0f) * WW - 1.0f) * 0.5f;
        float fy = ((gy + 1.0f) * HH - 1.0f) * 0.5f;
        float fx0 = floorf(fx), fy0 = floorf(fy);
        float wx1 = fx - fx0, wy1 = fy - fy0;
        float wx0 = 1.0f - wx1, wy0 = 1.0f - wy1;
        int x0 = (int)fx0, y0 = (int)fy0;
        int x1 = x0 + 1, y1 = y0 + 1;
        int cx0 = min(max(x0, 0), WW - 1), cx1 = min(max(x1, 0), WW - 1);
        int cy0 = min(max(y0, 0), HH - 1), cy1 = min(max(y1, 0), HH - 1);
        float vx0 = (x0 >= 0 && x0 < WW) ? 1.0f : 0.0f;
        float vx1 = (x1 >= 0 && x1 < WW) ? 1.0f : 0.0f;
        float vy0 = (y0 >= 0 && y0 < HH) ? 1.0f : 0.0f;
        float vy1 = (y1 >= 0 && y1 < HH) ? 1.0f : 0.0f;
        float m00 = 1, m01 = 1, m10 = 1, m11 = 1;
        if (mb) {
            m00 = mb[cy0 * WW + cx0]; m01 = mb[cy0 * WW + cx1];
            m10 = mb[cy1 * WW + cx0]; m11 = mb[cy1 * WW + cx1];
        }
        float w00 = wx0 * wy0 * vx0 * vy0 * m00 * act;
        float w01 = wx1 * wy0 * vx1 * vy0 * m01 * act;
        float w10 = wx0 * wy1 * vx0 * vy1 * m10 * act;
        float w11 = wx1 * wy1 * vx1 * vy1 * m11 * act;
        int bx = min(max(x0, 0), WW - 2);
        int dd = x0 - bx;
        gc[px * 4 + 0] = (dd == 0 ? w00 : 0.f) + (dd == -1 ? w01 : 0.f);
        gc[px * 4 + 1] = (dd == 0 ? w01 : 0.f) + (dd ==  1 ? w00 : 0.f);
        gc[px * 4 + 2] = (dd == 0 ? w10 : 0.f) + (dd == -1 ? w11 : 0.f);
        gc[px * 4 + 3] = (dd == 0 ? w11 : 0.f) + (dd ==  1 ? w10 : 0.f);
        o4[px * 2 + 0] = nbase + cy0 * WW + bx;
        o4[px * 2 + 1] = nbase + cy1 * WW + bx;
    }
}

// ---------------------------------------------------------------------------
// Kernel 2: partial attention scores.
// Block = (b, h, wtile of 128 px, cchunk of 64 c). 256 thr = 4 cg x 64 lanes,
// each lane owns 2 adjacent pixels; each cg reduces 16 channels (ascending ci
// — out_kernel walks the same strip DESCENDING to harvest L3 residency).
// NOTE (R3 post-mortem): no manual software pipeline here — holding the
// prefetched windows across a conditional reload forced the register
// allocator to 64 VGPRs and pushed cf[] to scratch (+128 MB FETCH, +65 µs).
// The compiler's own in-loop scheduling plus 16 waves/CU is better.
// ---------------------------------------------------------------------------
__global__ __launch_bounds__(256, 4) void score_kernel(
    const float* __restrict__ x, const float* __restrict__ pt,
    const float* __restrict__ maskw, float* __restrict__ scoresP)
{
    int blk = xcd_swizzle(blockIdx.x, gridDim.x);
    int cc = blk & (NCC - 1);
    int wt = (blk >> 2) & 1;
    int t  = blk >> 3;
    int h  = t % HH;
    int b  = t / HH;

    int tid = threadIdx.x;
    int lane = tid & 63;
    int cg   = tid >> 6;
    int px0  = wt * 128 + 2 * lane;
    float act = (px0 < WW) ? 1.0f : 0.0f;
    v2f act2 = {act, act};
    int cstart = cc * (CC / NCC) + cg * CI_PER_CG;

    XF X[LL];
#pragma unroll
    for (int l = 0; l < LL; ++l) X[l] = load_xf(pt, b, l);
    bool ident0 = is_trans(X[0]) && X[0].t02 == 0.0f && X[0].t12 == 0.0f;
    bool ftrans = ident0 && is_trans(X[1]) && is_trans(X[2])
                         && is_trans(X[3]) && is_trans(X[4]);

    v2f s[LL];
#pragma unroll
    for (int l = 0; l < LL; ++l) s[l] = (v2f){0.f, 0.f};

    if (ftrans) {
        int f0off = b * LL * CHW + cstart * HW + h * WW + min(px0, WW - 2);
        float cf[4][16];
        int o[8];
#pragma unroll
        for (int l = 1; l < LL; ++l)
            setup_trans(l, b, h, px0, act, X[l], maskw, cstart, cf[l - 1], &o[(l - 1) * 2]);

        for (int ci = 0; ci < CI_PER_CG; ++ci) {
            v2f f0 = ld2v(x + f0off) * act2;  f0off += HW;
            s[0] += f0 * f0;
#pragma unroll
            for (int l = 1; l < LL; ++l) {
                v4f F0 = ld4v(x + o[(l - 1) * 2 + 0]);
                v4f F1 = ld4v(x + o[(l - 1) * 2 + 1]);
                o[(l - 1) * 2 + 0] += HW;
                o[(l - 1) * 2 + 1] += HW;
                v2f fl;
                fl.x = dot8(&cf[l - 1][0], F0, F1);
                fl.y = dot8(&cf[l - 1][8], F0, F1);
                s[l] += f0 * fl;
            }
        }
    } else {
        float gc[LL][8];
        int go[LL][4];
#pragma unroll
        for (int l = 0; l < LL; ++l)
            setup_gen(l, b, h, px0, act, X[l], maskw, cstart, gc[l], go[l]);

        for (int ci = 0; ci < CI_PER_CG; ++ci) {
            v2f fv[LL];
#pragma unroll
            for (int l = 0; l < LL; ++l) {
                v2f R00 = ld2v(x + go[l][0]);
                v2f R01 = ld2v(x + go[l][1]);
                v2f R10 = ld2v(x + go[l][2]);
                v2f R11 = ld2v(x + go[l][3]);
#pragma unroll
                for (int k = 0; k < 4; ++k) go[l][k] += HW;
                fv[l].x = gc[l][0]*R00.x + gc[l][1]*R00.y + gc[l][2]*R01.x + gc[l][3]*R01.y;
                fv[l].y = gc[l][4]*R10.x + gc[l][5]*R10.y + gc[l][6]*R11.x + gc[l][7]*R11.y;
            }
#pragma unroll
            for (int l = 0; l < LL; ++l) s[l] += fv[0] * fv[l];
        }
    }

    __shared__ v2f sred[4][LL][64];
#pragma unroll
    for (int l = 0; l < LL; ++l) sred[cg][l][lane] = s[l];
    __syncthreads();

    if (tid < 64 && px0 < WW) {
        int p = h * WW + px0;
#pragma unroll
        for (int l = 0; l < LL; ++l) {
            v2f v = (sred[0][l][lane] + sred[1][l][lane]
                   + sred[2][l][lane] + sred[3][l][lane]) * 0.0625f;  // /sqrt(256)
            st2v(&scoresP[((cc * BB + b) * LL + l) * HW + p], v);
        }
    }
}

// ---------------------------------------------------------------------------
// Kernel 3: softmax over L (per thread from score partials) + weighted gather.
// Attention folded into tap coefficients. ci walks DESCENDING (tail of
// score's stream is the freshest L3 data). Plain stores — 8B non-temporal
// stores measured 2.4x write amplification (R3: WRITE_SIZE 122.7 MB vs
// 51.6 MB ideal), so NT is net-negative here.
// ---------------------------------------------------------------------------
__global__ __launch_bounds__(256, 4) void out_kernel(
    const float* __restrict__ x, const float* __restrict__ pt,
    const float* __restrict__ maskw, const float* __restrict__ scoresP,
    float* __restrict__ out)
{
    int blk = xcd_swizzle(blockIdx.x, gridDim.x);
    int cc = blk & (NCC - 1);
    int wt = (blk >> 2) & 1;
    int t  = blk >> 3;
    int h  = t % HH;
    int b  = t / HH;

    int tid = threadIdx.x;
    int lane = tid & 63;
    int cg   = tid >> 6;
    int px0  = wt * 128 + 2 * lane;
    float act = (px0 < WW) ? 1.0f : 0.0f;
    v2f act2 = {act, act};
    int cstart = cc * (CC / NCC) + cg * CI_PER_CG;

    // softmax over agents, per pixel pair (sum the 4 channel-chunk partials)
    v2f a[LL];
    {
        int p = min(h * WW + px0, HW - 2);
        v2f mx = {-1e30f, -1e30f};
#pragma unroll
        for (int l = 0; l < LL; ++l) {
            v2f sc = {0.f, 0.f};
#pragma unroll
            for (int q = 0; q < NCC; ++q)
                sc += ld2v(scoresP + ((q * BB + b) * LL + l) * HW + p);
            a[l] = sc;
            mx.x = fmaxf(mx.x, sc.x);
            mx.y = fmaxf(mx.y, sc.y);
        }
        v2f denom = {0.f, 0.f};
#pragma unroll
        for (int l = 0; l < LL; ++l) {
            a[l].x = __expf(a[l].x - mx.x);
            a[l].y = __expf(a[l].y - mx.y);
            denom += a[l];
        }
        v2f inv = {1.0f / denom.x, 1.0f / denom.y};
#pragma unroll
        for (int l = 0; l < LL; ++l) a[l] *= inv;
    }

    XF X[LL];
#pragma unroll
    for (int l = 0; l < LL; ++l) X[l] = load_xf(pt, b, l);
    bool ident0 = is_trans(X[0]) && X[0].t02 == 0.0f && X[0].t12 == 0.0f;
    bool ftrans = ident0 && is_trans(X[1]) && is_trans(X[2])
                         && is_trans(X[3]) && is_trans(X[4]);

    // start at the LAST channel of this cg's strip and walk down
    int obase = b * CHW + cstart * HW + h * WW + px0 + (CI_PER_CG - 1) * HW;
    bool doStore = (px0 < WW);

    if (ftrans) {
        int f0off = b * LL * CHW + cstart * HW + h * WW + min(px0, WW - 2)
                  + (CI_PER_CG - 1) * HW;
        float cf[4][16];
        int o[8];
#pragma unroll
        for (int l = 1; l < LL; ++l) {
            setup_trans(l, b, h, px0, act, X[l], maskw, cstart, cf[l - 1], &o[(l - 1) * 2]);
            o[(l - 1) * 2 + 0] += (CI_PER_CG - 1) * HW;
            o[(l - 1) * 2 + 1] += (CI_PER_CG - 1) * HW;
#pragma unroll
            for (int k = 0; k < 8; ++k) {           // fold attn per pixel
                cf[l - 1][k]     *= a[l].x;
                cf[l - 1][k + 8] *= a[l].y;
            }
        }
        v2f af0 = a[0] * act2;

        for (int ci = 0; ci < CI_PER_CG; ++ci) {
            v2f f0 = ld2v(x + f0off);  f0off -= HW;
            v2f ctx = af0 * f0;
#pragma unroll
            for (int l = 1; l < LL; ++l) {
                v4f F0 = ld4v(x + o[(l - 1) * 2 + 0]);
                v4f F1 = ld4v(x + o[(l - 1) * 2 + 1]);
                o[(l - 1) * 2 + 0] -= HW;
                o[(l - 1) * 2 + 1] -= HW;
                ctx.x += dot8(&cf[l - 1][0], F0, F1);
                ctx.y += dot8(&cf[l - 1][8], F0, F1);
            }
            if (doStore) st2v(&out[obase], ctx);
            obase -= HW;
        }
    } else {
        float gc[LL][8];
        int go[LL][4];
#pragma unroll
        for (int l = 0; l < LL; ++l) {
            setup_gen(l, b, h, px0, act, X[l], maskw, cstart, gc[l], go[l]);
#pragma unroll
            for (int k = 0; k < 4; ++k) {
                go[l][k] += (CI_PER_CG - 1) * HW;
            }
#pragma unroll
            for (int k = 0; k < 4; ++k) {
                gc[l][k]     *= a[l].x;
                gc[l][k + 4] *= a[l].y;
            }
        }
        for (int ci = 0; ci < CI_PER_CG; ++ci) {
            v2f ctx = {0.f, 0.f};
#pragma unroll
            for (int l = 0; l < LL; ++l) {
                v2f R00 = ld2v(x + go[l][0]);
                v2f R01 = ld2v(x + go[l][1]);
                v2f R10 = ld2v(x + go[l][2]);
                v2f R11 = ld2v(x + go[l][3]);
#pragma unroll
                for (int k = 0; k < 4; ++k) go[l][k] -= HW;
                ctx.x += gc[l][0]*R00.x + gc[l][1]*R00.y + gc[l][2]*R01.x + gc[l][3]*R01.y;
                ctx.y += gc[l][4]*R10.x + gc[l][5]*R10.y + gc[l][6]*R11.x + gc[l][7]*R11.y;
            }
            if (doStore) st2v(&out[obase], ctx);
            obase -= HW;
        }
    }
}

extern "C" void kernel_launch(void* const* d_in, const int* in_sizes, int n_in,
                              void* d_out, int out_size, void* d_ws, size_t ws_size,
                              hipStream_t stream)
{
    const float* x   = (const float*)d_in[0];   // (10, 256, 100, 252)
    const float* psm = (const float*)d_in[1];   // (10, 2, 100, 252)
    const float* pt  = (const float*)d_in[2];   // (2, 5, 5, 4, 4)
    float* out = (float*)d_out;                 // (2, 256, 100, 252)

    float* maskw  = (float*)d_ws;               // 4*HW floats
    float* scores = maskw + 4 * HW;             // NCC*B*L*HW floats

    mask_kernel<<<(4 * HW + 255) / 256, 256, 0, stream>>>(psm, maskw);
    score_kernel<<<BB * HH * 2 * NCC, 256, 0, stream>>>(x, pt, maskw, scores);
    out_kernel<<<BB * HH * 2 * NCC, 256, 0, stream>>>(x, pt, maskw, scores, out);
}

// Round 5
// 450.487 us; speedup vs baseline: 1.3321x; 1.0689x over previous
//
#include <hip/hip_runtime.h>
#include <math.h>

#define BB 2
#define LL 5
#define CC 256
#define HH 100
#define WW 252
#define HW (HH*WW)
#define CHW (CC*HW)
#define THRE_F 0.01f

// channel-chunking: 4 chunks x 64 channels; each of 4 wave-groups does 16
#define NCC 4
#define CI_PER_CG 16

typedef float v2f __attribute__((ext_vector_type(2)));
typedef float v4f __attribute__((ext_vector_type(4)));

__device__ __forceinline__ v2f ld2v(const float* p) {
    v2f v; __builtin_memcpy(&v, p, 8); return v;
}
__device__ __forceinline__ v4f ld4v(const float* p) {
    v4f v; __builtin_memcpy(&v, p, 16); return v;
}
__device__ __forceinline__ void st2v(float* p, v2f v) {
    __builtin_memcpy(p, &v, 8);
}
__device__ __forceinline__ float dot8(const float* c, v4f A, v4f B) {
    return c[0]*A.x + c[1]*A.y + c[2]*A.z + c[3]*A.w
         + c[4]*B.x + c[5]*B.y + c[6]*B.z + c[7]*B.w;
}

// XCD-aware bijective swizzle: dispatch i lands on XCD i%8 (m09); give each
// XCD a contiguous chunk of logical block ids so h and h+1 share an L2.
__device__ __forceinline__ int xcd_swizzle(int blk, int nblk) {
    int q = nblk >> 3;              // nblk % 8 == 0 for our grids
    return (blk & 7) * q + (blk >> 3);
}

// 5x5 gaussian, sigma=1 (float literals, no runtime exp)
__device__ const float GW[5][5] = {
    {0.002915024f, 0.013064233f, 0.021539279f, 0.013064233f, 0.002915024f},
    {0.013064233f, 0.058549832f, 0.096532353f, 0.058549832f, 0.013064233f},
    {0.021539279f, 0.096532353f, 0.159154943f, 0.096532353f, 0.021539279f},
    {0.013064233f, 0.058549832f, 0.096532353f, 0.058549832f, 0.013064233f},
    {0.002915024f, 0.013064233f, 0.021539279f, 0.013064233f, 0.002915024f},
};

// ---------------------------------------------------------------------------
// Kernel 1: confidence mask for odd agents. m in [0,4): n in {1,3,6,8}
// ---------------------------------------------------------------------------
__global__ void mask_kernel(const float* __restrict__ psm, float* __restrict__ mask)
{
    int idx = blockIdx.x * blockDim.x + threadIdx.x;
    if (idx >= 4 * HW) return;
    int m = idx / HW;
    int p = idx - m * HW;
    int h = p / WW;
    int w = p - h * WW;
    int n = (m >> 1) * LL + ((m & 1) * 2 + 1);
    const float* base0 = psm + (size_t)n * 2 * HW;
    const float* base1 = base0 + HW;

    float acc = 0.0f;
#pragma unroll
    for (int i = 0; i < 5; ++i) {
        int yy = h + i - 2;
        if (yy < 0 || yy >= HH) continue;
#pragma unroll
        for (int j = 0; j < 5; ++j) {
            int xx = w + j - 2;
            if (xx < 0 || xx >= WW) continue;
            float v = fmaxf(base0[yy * WW + xx], base1[yy * WW + xx]);
            acc += GW[i][j] / (1.0f + __expf(-v));
        }
    }
    mask[idx] = (acc > THRE_F) ? 1.0f : 0.0f;
}

// ---------------------------------------------------------------------------
// Transform decode (theta row pair, pre-scaled per reference)
// ---------------------------------------------------------------------------
struct XF { float t00, t01, t02, t10, t11, t12; };

__device__ __forceinline__ XF load_xf(const float* __restrict__ pt, int b, int l) {
    const float* M = pt + (size_t)(b * LL * LL + l) * 16;  // pairwise[b,0,l]
    XF X;
    X.t00 = M[0];
    X.t01 = M[1] * (100.0f / 252.0f);
    X.t02 = M[3] / 403.2f * 2.0f;
    X.t10 = M[4] * (252.0f / 100.0f);
    X.t11 = M[5];
    X.t12 = M[7] / 160.0f * 2.0f;
    return X;
}
__device__ __forceinline__ bool is_trans(const XF& X) {
    return X.t00 == 1.0f && X.t01 == 0.0f && X.t10 == 0.0f && X.t11 == 1.0f;
}

// ---------------------------------------------------------------------------
// Translation fast-path tap setup for one agent l: lane owns pixels px0,px0+1.
// One 4-float window at even col covers all x-taps of both pixels; borders,
// validity, conv-mask and tile-activity folded into cf[16]:
//   cf[px*8 + row*4 + e]  multiplies window element e of row (y0,y1).
// ---------------------------------------------------------------------------
__device__ __forceinline__ void setup_trans(
    int l, int b, int h, int px0, float act, const XF& X,
    const float* __restrict__ maskw, int cstart,
    float cf[16], int o2[2])
{
    float tx = X.t02 * (WW * 0.5f);
    float ty = X.t12 * (HH * 0.5f);
    int ix = (int)floorf(tx);
    int iy = (int)floorf(ty);
    float wx1 = tx - (float)ix, wx0 = 1.0f - wx1;
    float wy1 = ty - (float)iy, wy0 = 1.0f - wy1;
    int y0 = h + iy, y1 = y0 + 1;
    int cy0 = min(max(y0, 0), HH - 1), cy1 = min(max(y1, 0), HH - 1);
    float vy0 = (y0 >= 0 && y0 < HH) ? 1.0f : 0.0f;
    float vy1 = (y1 >= 0 && y1 < HH) ? 1.0f : 0.0f;

    int craw = px0 + ix;
    int col = craw & ~1;
    col = min(max(col, 0), WW - 4);
    int d = craw - col;          // <= 3 (may be negative at left border)

    const float* mb = nullptr;
    if (l & 1) mb = maskw + (size_t)(b * 2 + (l >> 1)) * HW;

#pragma unroll
    for (int k = 0; k < 16; ++k) cf[k] = 0.0f;
#pragma unroll
    for (int px = 0; px < 2; ++px) {
#pragma unroll
        for (int r = 0; r < 2; ++r) {
#pragma unroll
            for (int t = 0; t < 2; ++t) {
                int xt = craw + px + t;
                float vx  = (xt >= 0 && xt < WW) ? 1.0f : 0.0f;
                float wcol = t ? wx1 : wx0;
                float wrow = r ? wy1 : wy0;
                float vyw  = r ? vy1 : vy0;
                float m = 1.0f;
                if (mb) {
                    int cx = min(max(xt, 0), WW - 1);
                    int cy = r ? cy1 : cy0;
                    m = mb[cy * WW + cx];
                }
                float wgt = wcol * wrow * vyw * vx * m * act;
                int e = d + px + t;
#pragma unroll
                for (int k = 0; k < 4; ++k)
                    if (e == k) cf[px * 8 + r * 4 + k] += wgt;
            }
        }
    }
    int nbase = (b * LL + l) * CHW + cstart * HW;
    o2[0] = nbase + cy0 * WW + col;
    o2[1] = nbase + cy1 * WW + col;
}

// ---------------------------------------------------------------------------
// General-affine tap setup (fallback; not exercised by translation inputs).
// Per pixel px: float2 loads at rows y0/y1, coefs gc[px*4 + {a0,b0,a1,b1}].
// ---------------------------------------------------------------------------
__device__ __forceinline__ void setup_gen(
    int l, int b, int h, int px0, float act, const XF& X,
    const float* __restrict__ maskw, int cstart,
    float gc[8], int o4[4])
{
    const float* mb = nullptr;
    if (l & 1) mb = maskw + (size_t)(b * 2 + (l >> 1)) * HW;
    float ysn = (h + 0.5f) * (2.0f / HH) - 1.0f;
    int nbase = (b * LL + l) * CHW + cstart * HW;

#pragma unroll
    for (int px = 0; px < 2; ++px) {
        float xsn = (px0 + px + 0.5f) * (2.0f / WW) - 1.0f;
        float gx = X.t00 * xsn + X.t01 * ysn + X.t02;
        float gy = X.t10 * xsn + X.t11 * ysn + X.t12;
        float fx = ((gx + 1.0f) * WW - 1.0f) * 0.5f;
        float fy = ((gy + 1.0f) * HH - 1.0f) * 0.5f;
        float fx0 = floorf(fx), fy0 = floorf(fy);
        float wx1 = fx - fx0, wy1 = fy - fy0;
        float wx0 = 1.0f - wx1, wy0 = 1.0f - wy1;
        int x0 = (int)fx0, y0 = (int)fy0;
        int x1 = x0 + 1, y1 = y0 + 1;
        int cx0 = min(max(x0, 0), WW - 1), cx1 = min(max(x1, 0), WW - 1);
        int cy0 = min(max(y0, 0), HH - 1), cy1 = min(max(y1, 0), HH - 1);
        float vx0 = (x0 >= 0 && x0 < WW) ? 1.0f : 0.0f;
        float vx1 = (x1 >= 0 && x1 < WW) ? 1.0f : 0.0f;
        float vy0 = (y0 >= 0 && y0 < HH) ? 1.0f : 0.0f;
        float vy1 = (y1 >= 0 && y1 < HH) ? 1.0f : 0.0f;
        float m00 = 1, m01 = 1, m10 = 1, m11 = 1;
        if (mb) {
            m00 = mb[cy0 * WW + cx0]; m01 = mb[cy0 * WW + cx1];
            m10 = mb[cy1 * WW + cx0]; m11 = mb[cy1 * WW + cx1];
        }
        float w00 = wx0 * wy0 * vx0 * vy0 * m00 * act;
        float w01 = wx1 * wy0 * vx1 * vy0 * m01 * act;
        float w10 = wx0 * wy1 * vx0 * vy1 * m10 * act;
        float w11 = wx1 * wy1 * vx1 * vy1 * m11 * act;
        int bx = min(max(x0, 0), WW - 2);
        int dd = x0 - bx;
        gc[px * 4 + 0] = (dd == 0 ? w00 : 0.f) + (dd == -1 ? w01 : 0.f);
        gc[px * 4 + 1] = (dd == 0 ? w01 : 0.f) + (dd ==  1 ? w00 : 0.f);
        gc[px * 4 + 2] = (dd == 0 ? w10 : 0.f) + (dd == -1 ? w11 : 0.f);
        gc[px * 4 + 3] = (dd == 0 ? w11 : 0.f) + (dd ==  1 ? w10 : 0.f);
        o4[px * 2 + 0] = nbase + cy0 * WW + bx;
        o4[px * 2 + 1] = nbase + cy1 * WW + bx;
    }
}

// ---------------------------------------------------------------------------
// Kernel 2: partial attention scores.
// Block = (b, h, wtile of 128 px, cchunk of 64 c). 256 thr = 4 cg x 64 lanes,
// each lane owns 2 adjacent pixels; each cg reduces 16 channels.
// Software-pipelined with UNCONDITIONAL prefetch + peeled last iteration.
// (R3 lesson: a conditional reload `if(more)` created divergent phi-nodes and
// pushed cf[] to scratch. No conditionals inside the loop this time;
// launch_bounds relaxed to 3 waves/EU so the pipeline's ~150 VGPR fit.)
// ---------------------------------------------------------------------------
__global__ __launch_bounds__(256, 3) void score_kernel(
    const float* __restrict__ x, const float* __restrict__ pt,
    const float* __restrict__ maskw, float* __restrict__ scoresP)
{
    int blk = xcd_swizzle(blockIdx.x, gridDim.x);
    int cc = blk & (NCC - 1);
    int wt = (blk >> 2) & 1;
    int t  = blk >> 3;
    int h  = t % HH;
    int b  = t / HH;

    int tid = threadIdx.x;
    int lane = tid & 63;
    int cg   = tid >> 6;
    int px0  = wt * 128 + 2 * lane;
    float act = (px0 < WW) ? 1.0f : 0.0f;
    v2f act2 = {act, act};
    int cstart = cc * (CC / NCC) + cg * CI_PER_CG;

    XF X[LL];
#pragma unroll
    for (int l = 0; l < LL; ++l) X[l] = load_xf(pt, b, l);
    bool ident0 = is_trans(X[0]) && X[0].t02 == 0.0f && X[0].t12 == 0.0f;
    bool ftrans = ident0 && is_trans(X[1]) && is_trans(X[2])
                         && is_trans(X[3]) && is_trans(X[4]);

    v2f s[LL];
#pragma unroll
    for (int l = 0; l < LL; ++l) s[l] = (v2f){0.f, 0.f};

    if (ftrans) {
        int f0off = b * LL * CHW + cstart * HW + h * WW + min(px0, WW - 2);
        float cf[4][16];
        int o[8];
#pragma unroll
        for (int l = 1; l < LL; ++l)
            setup_trans(l, b, h, px0, act, X[l], maskw, cstart, cf[l - 1], &o[(l - 1) * 2]);

        // prologue: load iteration 0
        v2f f0v = ld2v(x + f0off);  f0off += HW;
        v4f Fa[4], Fb[4];
#pragma unroll
        for (int l = 0; l < 4; ++l) {
            Fa[l] = ld4v(x + o[2 * l]);     o[2 * l]     += HW;
            Fb[l] = ld4v(x + o[2 * l + 1]); o[2 * l + 1] += HW;
        }

        // steady state: compute ci from held regs, prefetch ci+1 unconditionally
        for (int ci = 0; ci < CI_PER_CG - 1; ++ci) {
            v2f f0 = f0v * act2;
            f0v = ld2v(x + f0off); f0off += HW;
            s[0] += f0 * f0;
#pragma unroll
            for (int l = 0; l < 4; ++l) {
                v4f A = Fa[l], B = Fb[l];
                Fa[l] = ld4v(x + o[2 * l]);     o[2 * l]     += HW;
                Fb[l] = ld4v(x + o[2 * l + 1]); o[2 * l + 1] += HW;
                v2f fl;
                fl.x = dot8(&cf[l][0], A, B);
                fl.y = dot8(&cf[l][8], A, B);
                s[l + 1] += f0 * fl;
            }
        }
        // epilogue: last iteration, no prefetch
        {
            v2f f0 = f0v * act2;
            s[0] += f0 * f0;
#pragma unroll
            for (int l = 0; l < 4; ++l) {
                v2f fl;
                fl.x = dot8(&cf[l][0], Fa[l], Fb[l]);
                fl.y = dot8(&cf[l][8], Fa[l], Fb[l]);
                s[l + 1] += f0 * fl;
            }
        }
    } else {
        float gc[LL][8];
        int go[LL][4];
#pragma unroll
        for (int l = 0; l < LL; ++l)
            setup_gen(l, b, h, px0, act, X[l], maskw, cstart, gc[l], go[l]);

        for (int ci = 0; ci < CI_PER_CG; ++ci) {
            v2f fv[LL];
#pragma unroll
            for (int l = 0; l < LL; ++l) {
                v2f R00 = ld2v(x + go[l][0]);
                v2f R01 = ld2v(x + go[l][1]);
                v2f R10 = ld2v(x + go[l][2]);
                v2f R11 = ld2v(x + go[l][3]);
#pragma unroll
                for (int k = 0; k < 4; ++k) go[l][k] += HW;
                fv[l].x = gc[l][0]*R00.x + gc[l][1]*R00.y + gc[l][2]*R01.x + gc[l][3]*R01.y;
                fv[l].y = gc[l][4]*R10.x + gc[l][5]*R10.y + gc[l][6]*R11.x + gc[l][7]*R11.y;
            }
#pragma unroll
            for (int l = 0; l < LL; ++l) s[l] += fv[0] * fv[l];
        }
    }

    __shared__ v2f sred[4][LL][64];
#pragma unroll
    for (int l = 0; l < LL; ++l) sred[cg][l][lane] = s[l];
    __syncthreads();

    if (tid < 64 && px0 < WW) {
        int p = h * WW + px0;
#pragma unroll
        for (int l = 0; l < LL; ++l) {
            v2f v = (sred[0][l][lane] + sred[1][l][lane]
                   + sred[2][l][lane] + sred[3][l][lane]) * 0.0625f;  // /sqrt(256)
            st2v(&scoresP[((cc * BB + b) * LL + l) * HW + p], v);
        }
    }
}

// ---------------------------------------------------------------------------
// Kernel 3: softmax over L (per thread from score partials) + weighted gather.
// Attention folded into tap coefficients. ci walks DESCENDING (tail of
// score's stream is the freshest L3 data). Plain stores (NT measured 2.4x
// write amplification in R3). Same unconditional-prefetch pipeline as score.
// ---------------------------------------------------------------------------
__global__ __launch_bounds__(256, 3) void out_kernel(
    const float* __restrict__ x, const float* __restrict__ pt,
    const float* __restrict__ maskw, const float* __restrict__ scoresP,
    float* __restrict__ out)
{
    int blk = xcd_swizzle(blockIdx.x, gridDim.x);
    int cc = blk & (NCC - 1);
    int wt = (blk >> 2) & 1;
    int t  = blk >> 3;
    int h  = t % HH;
    int b  = t / HH;

    int tid = threadIdx.x;
    int lane = tid & 63;
    int cg   = tid >> 6;
    int px0  = wt * 128 + 2 * lane;
    float act = (px0 < WW) ? 1.0f : 0.0f;
    v2f act2 = {act, act};
    int cstart = cc * (CC / NCC) + cg * CI_PER_CG;

    // softmax over agents, per pixel pair (sum the 4 channel-chunk partials)
    v2f a[LL];
    {
        int p = min(h * WW + px0, HW - 2);
        v2f mx = {-1e30f, -1e30f};
#pragma unroll
        for (int l = 0; l < LL; ++l) {
            v2f sc = {0.f, 0.f};
#pragma unroll
            for (int q = 0; q < NCC; ++q)
                sc += ld2v(scoresP + ((q * BB + b) * LL + l) * HW + p);
            a[l] = sc;
            mx.x = fmaxf(mx.x, sc.x);
            mx.y = fmaxf(mx.y, sc.y);
        }
        v2f denom = {0.f, 0.f};
#pragma unroll
        for (int l = 0; l < LL; ++l) {
            a[l].x = __expf(a[l].x - mx.x);
            a[l].y = __expf(a[l].y - mx.y);
            denom += a[l];
        }
        v2f inv = {1.0f / denom.x, 1.0f / denom.y};
#pragma unroll
        for (int l = 0; l < LL; ++l) a[l] *= inv;
    }

    XF X[LL];
#pragma unroll
    for (int l = 0; l < LL; ++l) X[l] = load_xf(pt, b, l);
    bool ident0 = is_trans(X[0]) && X[0].t02 == 0.0f && X[0].t12 == 0.0f;
    bool ftrans = ident0 && is_trans(X[1]) && is_trans(X[2])
                         && is_trans(X[3]) && is_trans(X[4]);

    // start at the LAST channel of this cg's strip and walk down
    int obase = b * CHW + cstart * HW + h * WW + px0 + (CI_PER_CG - 1) * HW;
    bool doStore = (px0 < WW);

    if (ftrans) {
        int f0off = b * LL * CHW + cstart * HW + h * WW + min(px0, WW - 2)
                  + (CI_PER_CG - 1) * HW;
        float cf[4][16];
        int o[8];
#pragma unroll
        for (int l = 1; l < LL; ++l) {
            setup_trans(l, b, h, px0, act, X[l], maskw, cstart, cf[l - 1], &o[(l - 1) * 2]);
            o[(l - 1) * 2 + 0] += (CI_PER_CG - 1) * HW;
            o[(l - 1) * 2 + 1] += (CI_PER_CG - 1) * HW;
#pragma unroll
            for (int k = 0; k < 8; ++k) {           // fold attn per pixel
                cf[l - 1][k]     *= a[l].x;
                cf[l - 1][k + 8] *= a[l].y;
            }
        }
        v2f af0 = a[0] * act2;

        // prologue: load first (topmost) channel's operands
        v2f f0v = ld2v(x + f0off);  f0off -= HW;
        v4f Fa[4], Fb[4];
#pragma unroll
        for (int l = 0; l < 4; ++l) {
            Fa[l] = ld4v(x + o[2 * l]);     o[2 * l]     -= HW;
            Fb[l] = ld4v(x + o[2 * l + 1]); o[2 * l + 1] -= HW;
        }

        for (int ci = 0; ci < CI_PER_CG - 1; ++ci) {
            v2f f0 = f0v;
            f0v = ld2v(x + f0off); f0off -= HW;
            v2f ctx = af0 * f0;
#pragma unroll
            for (int l = 0; l < 4; ++l) {
                v4f A = Fa[l], B = Fb[l];
                Fa[l] = ld4v(x + o[2 * l]);     o[2 * l]     -= HW;
                Fb[l] = ld4v(x + o[2 * l + 1]); o[2 * l + 1] -= HW;
                ctx.x += dot8(&cf[l][0], A, B);
                ctx.y += dot8(&cf[l][8], A, B);
            }
            if (doStore) st2v(&out[obase], ctx);
            obase -= HW;
        }
        // epilogue: last (lowest) channel
        {
            v2f ctx = af0 * f0v;
#pragma unroll
            for (int l = 0; l < 4; ++l) {
                ctx.x += dot8(&cf[l][0], Fa[l], Fb[l]);
                ctx.y += dot8(&cf[l][8], Fa[l], Fb[l]);
            }
            if (doStore) st2v(&out[obase], ctx);
        }
    } else {
        float gc[LL][8];
        int go[LL][4];
#pragma unroll
        for (int l = 0; l < LL; ++l) {
            setup_gen(l, b, h, px0, act, X[l], maskw, cstart, gc[l], go[l]);
#pragma unroll
            for (int k = 0; k < 4; ++k) {
                go[l][k] += (CI_PER_CG - 1) * HW;
            }
#pragma unroll
            for (int k = 0; k < 4; ++k) {
                gc[l][k]     *= a[l].x;
                gc[l][k + 4] *= a[l].y;
            }
        }
        for (int ci = 0; ci < CI_PER_CG; ++ci) {
            v2f ctx = {0.f, 0.f};
#pragma unroll
            for (int l = 0; l < LL; ++l) {
                v2f R00 = ld2v(x + go[l][0]);
                v2f R01 = ld2v(x + go[l][1]);
                v2f R10 = ld2v(x + go[l][2]);
                v2f R11 = ld2v(x + go[l][3]);
#pragma unroll
                for (int k = 0; k < 4; ++k) go[l][k] -= HW;
                ctx.x += gc[l][0]*R00.x + gc[l][1]*R00.y + gc[l][2]*R01.x + gc[l][3]*R01.y;
                ctx.y += gc[l][4]*R10.x + gc[l][5]*R10.y + gc[l][6]*R11.x + gc[l][7]*R11.y;
            }
            if (doStore) st2v(&out[obase], ctx);
            obase -= HW;
        }
    }
}

extern "C" void kernel_launch(void* const* d_in, const int* in_sizes, int n_in,
                              void* d_out, int out_size, void* d_ws, size_t ws_size,
                              hipStream_t stream)
{
    const float* x   = (const float*)d_in[0];   // (10, 256, 100, 252)
    const float* psm = (const float*)d_in[1];   // (10, 2, 100, 252)
    const float* pt  = (const float*)d_in[2];   // (2, 5, 5, 4, 4)
    float* out = (float*)d_out;                 // (2, 256, 100, 252)

    float* maskw  = (float*)d_ws;               // 4*HW floats
    float* scores = maskw + 4 * HW;             // NCC*B*L*HW floats

    mask_kernel<<<(4 * HW + 255) / 256, 256, 0, stream>>>(psm, maskw);
    score_kernel<<<BB * HH * 2 * NCC, 256, 0, stream>>>(x, pt, maskw, scores);
    out_kernel<<<BB * HH * 2 * NCC, 256, 0, stream>>>(x, pt, maskw, scores, out);
}

// Round 6
// 447.486 us; speedup vs baseline: 1.3410x; 1.0067x over previous
//
#include <hip/hip_runtime.h>
#include <math.h>

#define BB 2
#define LL 5
#define CC 256
#define HH 100
#define WW 252
#define HW (HH*WW)
#define CHW (CC*HW)
#define THRE_F 0.01f

// channel-chunking: 4 chunks x 64 channels; each of 4 wave-groups does 16
#define NCC 4
#define CI_PER_CG 16

typedef float v2f __attribute__((ext_vector_type(2)));
typedef float v4f __attribute__((ext_vector_type(4)));

__device__ __forceinline__ v2f ld2v(const float* p) {
    v2f v; __builtin_memcpy(&v, p, 8); return v;
}
__device__ __forceinline__ v4f ld4v(const float* p) {
    v4f v; __builtin_memcpy(&v, p, 16); return v;
}
__device__ __forceinline__ void st2v(float* p, v2f v) {
    __builtin_memcpy(p, &v, 8);
}
__device__ __forceinline__ float dot8(const float* c, v4f A, v4f B) {
    return c[0]*A.x + c[1]*A.y + c[2]*A.z + c[3]*A.w
         + c[4]*B.x + c[5]*B.y + c[6]*B.z + c[7]*B.w;
}

// XCD-aware bijective swizzle: dispatch i lands on XCD i%8 (m09); give each
// XCD a contiguous chunk of logical block ids so h and h+1 share an L2.
__device__ __forceinline__ int xcd_swizzle(int blk, int nblk) {
    int q = nblk >> 3;              // nblk % 8 == 0 for our grids
    return (blk & 7) * q + (blk >> 3);
}

// 5x5 gaussian, sigma=1 (float literals, no runtime exp)
__device__ const float GW[5][5] = {
    {0.002915024f, 0.013064233f, 0.021539279f, 0.013064233f, 0.002915024f},
    {0.013064233f, 0.058549832f, 0.096532353f, 0.058549832f, 0.013064233f},
    {0.021539279f, 0.096532353f, 0.159154943f, 0.096532353f, 0.021539279f},
    {0.013064233f, 0.058549832f, 0.096532353f, 0.058549832f, 0.013064233f},
    {0.002915024f, 0.013064233f, 0.021539279f, 0.013064233f, 0.002915024f},
};

// ---------------------------------------------------------------------------
// Kernel 1: confidence mask for odd agents. m in [0,4): n in {1,3,6,8}
// ---------------------------------------------------------------------------
__global__ void mask_kernel(const float* __restrict__ psm, float* __restrict__ mask)
{
    int idx = blockIdx.x * blockDim.x + threadIdx.x;
    if (idx >= 4 * HW) return;
    int m = idx / HW;
    int p = idx - m * HW;
    int h = p / WW;
    int w = p - h * WW;
    int n = (m >> 1) * LL + ((m & 1) * 2 + 1);
    const float* base0 = psm + (size_t)n * 2 * HW;
    const float* base1 = base0 + HW;

    float acc = 0.0f;
#pragma unroll
    for (int i = 0; i < 5; ++i) {
        int yy = h + i - 2;
        if (yy < 0 || yy >= HH) continue;
#pragma unroll
        for (int j = 0; j < 5; ++j) {
            int xx = w + j - 2;
            if (xx < 0 || xx >= WW) continue;
            float v = fmaxf(base0[yy * WW + xx], base1[yy * WW + xx]);
            acc += GW[i][j] / (1.0f + __expf(-v));
        }
    }
    mask[idx] = (acc > THRE_F) ? 1.0f : 0.0f;
}

// ---------------------------------------------------------------------------
// Transform decode (theta row pair, pre-scaled per reference)
// ---------------------------------------------------------------------------
struct XF { float t00, t01, t02, t10, t11, t12; };

__device__ __forceinline__ XF load_xf(const float* __restrict__ pt, int b, int l) {
    const float* M = pt + (size_t)(b * LL * LL + l) * 16;  // pairwise[b,0,l]
    XF X;
    X.t00 = M[0];
    X.t01 = M[1] * (100.0f / 252.0f);
    X.t02 = M[3] / 403.2f * 2.0f;
    X.t10 = M[4] * (252.0f / 100.0f);
    X.t11 = M[5];
    X.t12 = M[7] / 160.0f * 2.0f;
    return X;
}
__device__ __forceinline__ bool is_trans(const XF& X) {
    return X.t00 == 1.0f && X.t01 == 0.0f && X.t10 == 0.0f && X.t11 == 1.0f;
}

// ---------------------------------------------------------------------------
// Translation fast-path tap setup for one agent l: lane owns pixels px0,px0+1.
// One 4-float window at even col covers all x-taps of both pixels; borders,
// validity, conv-mask and tile-activity folded into cf[16]:
//   cf[px*8 + row*4 + e]  multiplies window element e of row (y0,y1).
// ---------------------------------------------------------------------------
__device__ __forceinline__ void setup_trans(
    int l, int b, int h, int px0, float act, const XF& X,
    const float* __restrict__ maskw, int cstart,
    float cf[16], int o2[2])
{
    float tx = X.t02 * (WW * 0.5f);
    float ty = X.t12 * (HH * 0.5f);
    int ix = (int)floorf(tx);
    int iy = (int)floorf(ty);
    float wx1 = tx - (float)ix, wx0 = 1.0f - wx1;
    float wy1 = ty - (float)iy, wy0 = 1.0f - wy1;
    int y0 = h + iy, y1 = y0 + 1;
    int cy0 = min(max(y0, 0), HH - 1), cy1 = min(max(y1, 0), HH - 1);
    float vy0 = (y0 >= 0 && y0 < HH) ? 1.0f : 0.0f;
    float vy1 = (y1 >= 0 && y1 < HH) ? 1.0f : 0.0f;

    int craw = px0 + ix;
    int col = craw & ~1;
    col = min(max(col, 0), WW - 4);
    int d = craw - col;          // <= 3 (may be negative at left border)

    const float* mb = nullptr;
    if (l & 1) mb = maskw + (size_t)(b * 2 + (l >> 1)) * HW;

#pragma unroll
    for (int k = 0; k < 16; ++k) cf[k] = 0.0f;
#pragma unroll
    for (int px = 0; px < 2; ++px) {
#pragma unroll
        for (int r = 0; r < 2; ++r) {
#pragma unroll
            for (int t = 0; t < 2; ++t) {
                int xt = craw + px + t;
                float vx  = (xt >= 0 && xt < WW) ? 1.0f : 0.0f;
                float wcol = t ? wx1 : wx0;
                float wrow = r ? wy1 : wy0;
                float vyw  = r ? vy1 : vy0;
                float m = 1.0f;
                if (mb) {
                    int cx = min(max(xt, 0), WW - 1);
                    int cy = r ? cy1 : cy0;
                    m = mb[cy * WW + cx];
                }
                float wgt = wcol * wrow * vyw * vx * m * act;
                int e = d + px + t;
#pragma unroll
                for (int k = 0; k < 4; ++k)
                    if (e == k) cf[px * 8 + r * 4 + k] += wgt;
            }
        }
    }
    int nbase = (b * LL + l) * CHW + cstart * HW;
    o2[0] = nbase + cy0 * WW + col;
    o2[1] = nbase + cy1 * WW + col;
}

// ---------------------------------------------------------------------------
// General-affine tap setup (fallback; not exercised by translation inputs).
// Per pixel px: float2 loads at rows y0/y1, coefs gc[px*4 + {a0,b0,a1,b1}].
// ---------------------------------------------------------------------------
__device__ __forceinline__ void setup_gen(
    int l, int b, int h, int px0, float act, const XF& X,
    const float* __restrict__ maskw, int cstart,
    float gc[8], int o4[4])
{
    const float* mb = nullptr;
    if (l & 1) mb = maskw + (size_t)(b * 2 + (l >> 1)) * HW;
    float ysn = (h + 0.5f) * (2.0f / HH) - 1.0f;
    int nbase = (b * LL + l) * CHW + cstart * HW;

#pragma unroll
    for (int px = 0; px < 2; ++px) {
        float xsn = (px0 + px + 0.5f) * (2.0f / WW) - 1.0f;
        float gx = X.t00 * xsn + X.t01 * ysn + X.t02;
        float gy = X.t10 * xsn + X.t11 * ysn + X.t12;
        float fx = ((gx + 1.0f) * WW - 1.0f) * 0.5f;
        float fy = ((gy + 1.0f) * HH - 1.0f) * 0.5f;
        float fx0 = floorf(fx), fy0 = floorf(fy);
        float wx1 = fx - fx0, wy1 = fy - fy0;
        float wx0 = 1.0f - wx1, wy0 = 1.0f - wy1;
        int x0 = (int)fx0, y0 = (int)fy0;
        int x1 = x0 + 1, y1 = y0 + 1;
        int cx0 = min(max(x0, 0), WW - 1), cx1 = min(max(x1, 0), WW - 1);
        int cy0 = min(max(y0, 0), HH - 1), cy1 = min(max(y1, 0), HH - 1);
        float vx0 = (x0 >= 0 && x0 < WW) ? 1.0f : 0.0f;
        float vx1 = (x1 >= 0 && x1 < WW) ? 1.0f : 0.0f;
        float vy0 = (y0 >= 0 && y0 < HH) ? 1.0f : 0.0f;
        float vy1 = (y1 >= 0 && y1 < HH) ? 1.0f : 0.0f;
        float m00 = 1, m01 = 1, m10 = 1, m11 = 1;
        if (mb) {
            m00 = mb[cy0 * WW + cx0]; m01 = mb[cy0 * WW + cx1];
            m10 = mb[cy1 * WW + cx0]; m11 = mb[cy1 * WW + cx1];
        }
        float w00 = wx0 * wy0 * vx0 * vy0 * m00 * act;
        float w01 = wx1 * wy0 * vx1 * vy0 * m01 * act;
        float w10 = wx0 * wy1 * vx0 * vy1 * m10 * act;
        float w11 = wx1 * wy1 * vx1 * vy1 * m11 * act;
        int bx = min(max(x0, 0), WW - 2);
        int dd = x0 - bx;
        gc[px * 4 + 0] = (dd == 0 ? w00 : 0.f) + (dd == -1 ? w01 : 0.f);
        gc[px * 4 + 1] = (dd == 0 ? w01 : 0.f) + (dd ==  1 ? w00 : 0.f);
        gc[px * 4 + 2] = (dd == 0 ? w10 : 0.f) + (dd == -1 ? w11 : 0.f);
        gc[px * 4 + 3] = (dd == 0 ? w11 : 0.f) + (dd ==  1 ? w10 : 0.f);
        o4[px * 2 + 0] = nbase + cy0 * WW + bx;
        o4[px * 2 + 1] = nbase + cy1 * WW + bx;
    }
}

// ---------------------------------------------------------------------------
// Kernel 2: partial attention scores.
// Block = (b, h, wtile of 128 px, cchunk of 64 c). 256 thr = 4 cg x 64 lanes,
// each lane owns 2 adjacent pixels; each cg reduces 16 channels.
// Software-pipelined with UNCONDITIONAL prefetch + peeled last iteration
// (R3 lesson: conditional reload pushed cf[] to scratch; R5 confirmed the
// rotated form gains ~30 µs).
// ---------------------------------------------------------------------------
__global__ __launch_bounds__(256, 3) void score_kernel(
    const float* __restrict__ x, const float* __restrict__ pt,
    const float* __restrict__ maskw, float* __restrict__ scoresP)
{
    int blk = xcd_swizzle(blockIdx.x, gridDim.x);
    int cc = blk & (NCC - 1);
    int wt = (blk >> 2) & 1;
    int t  = blk >> 3;
    int h  = t % HH;
    int b  = t / HH;

    int tid = threadIdx.x;
    int lane = tid & 63;
    int cg   = tid >> 6;
    int px0  = wt * 128 + 2 * lane;
    float act = (px0 < WW) ? 1.0f : 0.0f;
    v2f act2 = {act, act};
    int cstart = cc * (CC / NCC) + cg * CI_PER_CG;

    XF X[LL];
#pragma unroll
    for (int l = 0; l < LL; ++l) X[l] = load_xf(pt, b, l);
    bool ident0 = is_trans(X[0]) && X[0].t02 == 0.0f && X[0].t12 == 0.0f;
    bool ftrans = ident0 && is_trans(X[1]) && is_trans(X[2])
                         && is_trans(X[3]) && is_trans(X[4]);

    v2f s[LL];
#pragma unroll
    for (int l = 0; l < LL; ++l) s[l] = (v2f){0.f, 0.f};

    if (ftrans) {
        int f0off = b * LL * CHW + cstart * HW + h * WW + min(px0, WW - 2);
        float cf[4][16];
        int o[8];
#pragma unroll
        for (int l = 1; l < LL; ++l)
            setup_trans(l, b, h, px0, act, X[l], maskw, cstart, cf[l - 1], &o[(l - 1) * 2]);

        // prologue: load iteration 0
        v2f f0v = ld2v(x + f0off);  f0off += HW;
        v4f Fa[4], Fb[4];
#pragma unroll
        for (int l = 0; l < 4; ++l) {
            Fa[l] = ld4v(x + o[2 * l]);     o[2 * l]     += HW;
            Fb[l] = ld4v(x + o[2 * l + 1]); o[2 * l + 1] += HW;
        }

        // steady state: compute ci from held regs, prefetch ci+1 unconditionally
        for (int ci = 0; ci < CI_PER_CG - 1; ++ci) {
            v2f f0 = f0v * act2;
            f0v = ld2v(x + f0off); f0off += HW;
            s[0] += f0 * f0;
#pragma unroll
            for (int l = 0; l < 4; ++l) {
                v4f A = Fa[l], B = Fb[l];
                Fa[l] = ld4v(x + o[2 * l]);     o[2 * l]     += HW;
                Fb[l] = ld4v(x + o[2 * l + 1]); o[2 * l + 1] += HW;
                v2f fl;
                fl.x = dot8(&cf[l][0], A, B);
                fl.y = dot8(&cf[l][8], A, B);
                s[l + 1] += f0 * fl;
            }
        }
        // epilogue: last iteration, no prefetch
        {
            v2f f0 = f0v * act2;
            s[0] += f0 * f0;
#pragma unroll
            for (int l = 0; l < 4; ++l) {
                v2f fl;
                fl.x = dot8(&cf[l][0], Fa[l], Fb[l]);
                fl.y = dot8(&cf[l][8], Fa[l], Fb[l]);
                s[l + 1] += f0 * fl;
            }
        }
    } else {
        float gc[LL][8];
        int go[LL][4];
#pragma unroll
        for (int l = 0; l < LL; ++l)
            setup_gen(l, b, h, px0, act, X[l], maskw, cstart, gc[l], go[l]);

        for (int ci = 0; ci < CI_PER_CG; ++ci) {
            v2f fv[LL];
#pragma unroll
            for (int l = 0; l < LL; ++l) {
                v2f R00 = ld2v(x + go[l][0]);
                v2f R01 = ld2v(x + go[l][1]);
                v2f R10 = ld2v(x + go[l][2]);
                v2f R11 = ld2v(x + go[l][3]);
#pragma unroll
                for (int k = 0; k < 4; ++k) go[l][k] += HW;
                fv[l].x = gc[l][0]*R00.x + gc[l][1]*R00.y + gc[l][2]*R01.x + gc[l][3]*R01.y;
                fv[l].y = gc[l][4]*R10.x + gc[l][5]*R10.y + gc[l][6]*R11.x + gc[l][7]*R11.y;
            }
#pragma unroll
            for (int l = 0; l < LL; ++l) s[l] += fv[0] * fv[l];
        }
    }

    __shared__ v2f sred[4][LL][64];
#pragma unroll
    for (int l = 0; l < LL; ++l) sred[cg][l][lane] = s[l];
    __syncthreads();

    if (tid < 64 && px0 < WW) {
        int p = h * WW + px0;
#pragma unroll
        for (int l = 0; l < LL; ++l) {
            v2f v = (sred[0][l][lane] + sred[1][l][lane]
                   + sred[2][l][lane] + sred[3][l][lane]) * 0.0625f;  // /sqrt(256)
            st2v(&scoresP[((cc * BB + b) * LL + l) * HW + p], v);
        }
    }
}

// ---------------------------------------------------------------------------
// Kernel 3: softmax over L (per thread from score partials) + weighted gather.
// Attention folded into tap coefficients.
// L3 stack-order re-read: x (258 MB) ~ Infinity Cache (256 MB), so L3 holds
// score's LAST-read tiles. out therefore traverses EVERYTHING in reverse:
// block order reversed (gridDim-1-blockIdx before the XCD swizzle — keeps
// per-XCD chunk contiguity, just descending) AND ci descending within the
// strip. Plain stores (NT measured 2.4x write amplification in R3).
// Same unconditional-prefetch pipeline as score (R5).
// ---------------------------------------------------------------------------
__global__ __launch_bounds__(256, 3) void out_kernel(
    const float* __restrict__ x, const float* __restrict__ pt,
    const float* __restrict__ maskw, const float* __restrict__ scoresP,
    float* __restrict__ out)
{
    int blk = xcd_swizzle(gridDim.x - 1 - blockIdx.x, gridDim.x);
    int cc = blk & (NCC - 1);
    int wt = (blk >> 2) & 1;
    int t  = blk >> 3;
    int h  = t % HH;
    int b  = t / HH;

    int tid = threadIdx.x;
    int lane = tid & 63;
    int cg   = tid >> 6;
    int px0  = wt * 128 + 2 * lane;
    float act = (px0 < WW) ? 1.0f : 0.0f;
    v2f act2 = {act, act};
    int cstart = cc * (CC / NCC) + cg * CI_PER_CG;

    // softmax over agents, per pixel pair (sum the 4 channel-chunk partials)
    v2f a[LL];
    {
        int p = min(h * WW + px0, HW - 2);
        v2f mx = {-1e30f, -1e30f};
#pragma unroll
        for (int l = 0; l < LL; ++l) {
            v2f sc = {0.f, 0.f};
#pragma unroll
            for (int q = 0; q < NCC; ++q)
                sc += ld2v(scoresP + ((q * BB + b) * LL + l) * HW + p);
            a[l] = sc;
            mx.x = fmaxf(mx.x, sc.x);
            mx.y = fmaxf(mx.y, sc.y);
        }
        v2f denom = {0.f, 0.f};
#pragma unroll
        for (int l = 0; l < LL; ++l) {
            a[l].x = __expf(a[l].x - mx.x);
            a[l].y = __expf(a[l].y - mx.y);
            denom += a[l];
        }
        v2f inv = {1.0f / denom.x, 1.0f / denom.y};
#pragma unroll
        for (int l = 0; l < LL; ++l) a[l] *= inv;
    }

    XF X[LL];
#pragma unroll
    for (int l = 0; l < LL; ++l) X[l] = load_xf(pt, b, l);
    bool ident0 = is_trans(X[0]) && X[0].t02 == 0.0f && X[0].t12 == 0.0f;
    bool ftrans = ident0 && is_trans(X[1]) && is_trans(X[2])
                         && is_trans(X[3]) && is_trans(X[4]);

    // start at the LAST channel of this cg's strip and walk down
    int obase = b * CHW + cstart * HW + h * WW + px0 + (CI_PER_CG - 1) * HW;
    bool doStore = (px0 < WW);

    if (ftrans) {
        int f0off = b * LL * CHW + cstart * HW + h * WW + min(px0, WW - 2)
                  + (CI_PER_CG - 1) * HW;
        float cf[4][16];
        int o[8];
#pragma unroll
        for (int l = 1; l < LL; ++l) {
            setup_trans(l, b, h, px0, act, X[l], maskw, cstart, cf[l - 1], &o[(l - 1) * 2]);
            o[(l - 1) * 2 + 0] += (CI_PER_CG - 1) * HW;
            o[(l - 1) * 2 + 1] += (CI_PER_CG - 1) * HW;
#pragma unroll
            for (int k = 0; k < 8; ++k) {           // fold attn per pixel
                cf[l - 1][k]     *= a[l].x;
                cf[l - 1][k + 8] *= a[l].y;
            }
        }
        v2f af0 = a[0] * act2;

        // prologue: load first (topmost) channel's operands
        v2f f0v = ld2v(x + f0off);  f0off -= HW;
        v4f Fa[4], Fb[4];
#pragma unroll
        for (int l = 0; l < 4; ++l) {
            Fa[l] = ld4v(x + o[2 * l]);     o[2 * l]     -= HW;
            Fb[l] = ld4v(x + o[2 * l + 1]); o[2 * l + 1] -= HW;
        }

        for (int ci = 0; ci < CI_PER_CG - 1; ++ci) {
            v2f f0 = f0v;
            f0v = ld2v(x + f0off); f0off -= HW;
            v2f ctx = af0 * f0;
#pragma unroll
            for (int l = 0; l < 4; ++l) {
                v4f A = Fa[l], B = Fb[l];
                Fa[l] = ld4v(x + o[2 * l]);     o[2 * l]     -= HW;
                Fb[l] = ld4v(x + o[2 * l + 1]); o[2 * l + 1] -= HW;
                ctx.x += dot8(&cf[l][0], A, B);
                ctx.y += dot8(&cf[l][8], A, B);
            }
            if (doStore) st2v(&out[obase], ctx);
            obase -= HW;
        }
        // epilogue: last (lowest) channel
        {
            v2f ctx = af0 * f0v;
#pragma unroll
            for (int l = 0; l < 4; ++l) {
                ctx.x += dot8(&cf[l][0], Fa[l], Fb[l]);
                ctx.y += dot8(&cf[l][8], Fa[l], Fb[l]);
            }
            if (doStore) st2v(&out[obase], ctx);
        }
    } else {
        float gc[LL][8];
        int go[LL][4];
#pragma unroll
        for (int l = 0; l < LL; ++l) {
            setup_gen(l, b, h, px0, act, X[l], maskw, cstart, gc[l], go[l]);
#pragma unroll
            for (int k = 0; k < 4; ++k) {
                go[l][k] += (CI_PER_CG - 1) * HW;
            }
#pragma unroll
            for (int k = 0; k < 4; ++k) {
                gc[l][k]     *= a[l].x;
                gc[l][k + 4] *= a[l].y;
            }
        }
        for (int ci = 0; ci < CI_PER_CG; ++ci) {
            v2f ctx = {0.f, 0.f};
#pragma unroll
            for (int l = 0; l < LL; ++l) {
                v2f R00 = ld2v(x + go[l][0]);
                v2f R01 = ld2v(x + go[l][1]);
                v2f R10 = ld2v(x + go[l][2]);
                v2f R11 = ld2v(x + go[l][3]);
#pragma unroll
                for (int k = 0; k < 4; ++k) go[l][k] -= HW;
                ctx.x += gc[l][0]*R00.x + gc[l][1]*R00.y + gc[l][2]*R01.x + gc[l][3]*R01.y;
                ctx.y += gc[l][4]*R10.x + gc[l][5]*R10.y + gc[l][6]*R11.x + gc[l][7]*R11.y;
            }
            if (doStore) st2v(&out[obase], ctx);
            obase -= HW;
        }
    }
}

extern "C" void kernel_launch(void* const* d_in, const int* in_sizes, int n_in,
                              void* d_out, int out_size, void* d_ws, size_t ws_size,
                              hipStream_t stream)
{
    const float* x   = (const float*)d_in[0];   // (10, 256, 100, 252)
    const float* psm = (const float*)d_in[1];   // (10, 2, 100, 252)
    const float* pt  = (const float*)d_in[2];   // (2, 5, 5, 4, 4)
    float* out = (float*)d_out;                 // (2, 256, 100, 252)

    float* maskw  = (float*)d_ws;               // 4*HW floats
    float* scores = maskw + 4 * HW;             // NCC*B*L*HW floats

    mask_kernel<<<(4 * HW + 255) / 256, 256, 0, stream>>>(psm, maskw);
    score_kernel<<<BB * HH * 2 * NCC, 256, 0, stream>>>(x, pt, maskw, scores);
    out_kernel<<<BB * HH * 2 * NCC, 256, 0, stream>>>(x, pt, maskw, scores, out);
}